// Round 1
// 1502.912 us; speedup vs baseline: 1.0142x; 1.0142x over previous
//
#include <hip/hip_runtime.h>
#include <cstdint>
#include <cstddef>

// ---------------------------------------------------------------------------
// QuantMlp: out = fq(gelu(fq(x[reorder]) @ W1^T + b1)) @ W2^T + b2
// fq = per-token symmetric int8 fake-quant; q stored exactly in bf16, scale
// folded into the GEMM epilogue (rowScale).
//
// R2: replace the m97-style 128^2 2-barrier GEMM (616 TF, MfmaUtil 28%) with
// the 8-phase counted-vmcnt pipeline (guide §5 256^2 template, T2+T3+T4+T5+T1):
//  - BM=256, BK=64, 512 thr = 8 waves (2M x 4N), per-wave 128 x BN/4 output.
//  - LDS: 2 dbuf x 2 k-half slabs per matrix (A: 256x32, B: BNx32), 128/96 KB.
//  - per phase: ds_read frag subtile -> stage one half-K slab (global_load_lds
//    x16B) -> barrier -> lgkmcnt(0) -> setprio(1) -> 16(8) MFMA -> setprio(0)
//    -> [vmcnt(6|4) at phases 4/8] -> barrier.  Loads stay in flight across
//    barriers (never vmcnt(0) in the main loop).
//  - slab schedule (stage exactly one barrier after the slot's last reader):
//      p0:A[1][1]<-T+1,k1  p1:B[0][0]<-T+2,k0  p2:A[0][0]<-T+2,k0
//      p3:B[0][1]<-T+2,k1* p4:A[0][1]<-T+2,k1  p5:B[1][0]<-T+3,k0
//      p6:A[1][0]<-T+3,k0  p7:B[1][1]<-T+3,k1*      (* = vmcnt wait phases)
//  - XOR chunk swizzle (16B granularity): LDS slot (r,s) holds global chunk
//    s ^ ((r>>1)&3) -> conflict-free ds_read_b128 frags; inverse applied on
//    the per-lane GLOBAL source (gload_lds dest must stay linear).
//  - bijective XCD swizzle (m204) on the linear block id, N-fastest decode.
// BN=256 for fc1 (N=4608), BN=128 for fc2 (N=1152).
// ---------------------------------------------------------------------------

typedef __attribute__((ext_vector_type(8))) short short8;   // 8 bf16
typedef __attribute__((ext_vector_type(4))) float f32x4;

__device__ __forceinline__ float bf2f(unsigned short u) {
    return __uint_as_float(((unsigned)u) << 16);
}
__device__ __forceinline__ unsigned short f2bf(float f) {
    unsigned u = __float_as_uint(f);
    u += 0x7fff + ((u >> 16) & 1);   // round-to-nearest-even
    return (unsigned short)(u >> 16);
}

// async global->LDS, 16B per lane; LDS dest is wave-uniform base + lane*16
__device__ __forceinline__ void gload_lds16(const void* gptr, void* ldsptr) {
    typedef __attribute__((address_space(1))) const unsigned int gu32;
    typedef __attribute__((address_space(3))) unsigned int lu32;
    __builtin_amdgcn_global_load_lds((gu32*)gptr, (lu32*)ldsptr, 16, 0, 0);
}

// C[m][n] = rowScale[m] * sum_k A[m][k]*B[n][k] + bias[n]; A:[M,K], B:[N,K] bf16.
template <int BN, bool GELU>
__global__ __launch_bounds__(512, 2) void gemm8p(
    const unsigned short* __restrict__ A, const unsigned short* __restrict__ B,
    const float* __restrict__ bias, const float* __restrict__ rowScale,
    void* __restrict__ C, int M, int N, int K)
{
    constexpr int BM  = 256;
    constexpr int NR  = BN / 64;                   // n-frags per wave (4 | 2)
    constexpr int WCN = BN / 4;                    // per-wave col span
    constexpr int LB  = (BN * 32 * 2) / (512 * 16); // gloads per B slab (2 | 1)

    // [dbuf][k-half] slabs, each row = 32 bf16 (64B = 4 x 16B chunks)
    __shared__ unsigned short lA[2][2][BM * 32];
    __shared__ unsigned short lB[2][2][BN * 32];

    const int tid  = threadIdx.x;
    const int lane = tid & 63;
    const int wave = tid >> 6;
    const int wm = wave >> 2;            // 0..1
    const int wn = wave & 3;             // 0..3
    const int wbase = wave << 6;

    // bijective XCD swizzle (m204), then N-fastest decode for A-panel L2 reuse
    const int nbn = N / BN;
    {
    }
    const int nwg = (int)gridDim.x;
    const int orig = (int)blockIdx.x;
    const int qs = nwg >> 3, rs = nwg & 7;
    const int xcd = orig & 7, loc = orig >> 3;
    const int wg = (xcd < rs ? xcd * (qs + 1) : rs * (qs + 1) + (xcd - rs) * qs) + loc;
    const int bn = wg % nbn;
    const int bm = wg / nbn;

    const unsigned short* Ab = A + (size_t)bm * BM * K;
    const unsigned short* Bb = B + (size_t)bn * BN * K;

    // per-thread staging source offsets (elements). LDS slot (r,s) must hold
    // global chunk s ^ ((r>>1)&3); gload dest is linear in tid so invert on src.
    int srcA0, srcA1;
    {
        int idx = tid;       int r = idx >> 2, s = idx & 3;
        srcA0 = r * K + ((s ^ ((r >> 1) & 3)) << 3);
        idx = 512 + tid;     r = idx >> 2; s = idx & 3;
        srcA1 = r * K + ((s ^ ((r >> 1) & 3)) << 3);
    }

    auto stageA = [&](unsigned short* slab, int t, int kh) {
        const int ko = t * 64 + kh * 32;
        gload_lds16(Ab + srcA0 + ko, &slab[wbase * 8]);
        gload_lds16(Ab + srcA1 + ko, &slab[(512 + wbase) * 8]);
    };
    auto stageB = [&](unsigned short* slab, int t, int kh) {
        const int ko = t * 64 + kh * 32;
        gload_lds16(Bb + srcA0 + ko, &slab[wbase * 8]);
        if (LB == 2) gload_lds16(Bb + srcA1 + ko, &slab[(512 + wbase) * 8]);
    };

    // fragment-read lane offset: row R = base+lr, chunk q ^ ((R>>1)&3)
    // (base mult of 16 -> swizzle bits come from lr only). Conflict-free.
    const int q  = lane >> 4;
    const int lr = lane & 15;
    const int cidx = q ^ ((lr >> 1) & 3);
    const int laneOff = lr * 32 + cidx * 8;

    f32x4 acc[8][NR];
#pragma unroll
    for (int i = 0; i < 8; ++i)
#pragma unroll
        for (int j = 0; j < NR; ++j) acc[i][j] = (f32x4){0.f, 0.f, 0.f, 0.f};

    short8 bfrag[NR];

#define VM_WAIT()                                                            \
    do { if (BN == 256) asm volatile("s_waitcnt vmcnt(6)" ::: "memory");     \
         else           asm volatile("s_waitcnt vmcnt(4)" ::: "memory"); } while (0)

#define PH(RD, RKH, MH, STG_A, SD, SKH, STGT, VM_END)                                  \
    {                                                                                  \
        short8 af[4];                                                                  \
        if (MH == 0) {                                                                 \
            _Pragma("unroll")                                                          \
            for (int jj = 0; jj < NR; ++jj)                                            \
                bfrag[jj] = *(const short8*)&lB[RD][RKH][(wn * WCN + jj * 16) * 32 + laneOff]; \
        }                                                                              \
        _Pragma("unroll")                                                              \
        for (int ii = 0; ii < 4; ++ii)                                                 \
            af[ii] = *(const short8*)&lA[RD][RKH][(wm * 128 + MH * 64 + ii * 16) * 32 + laneOff]; \
        if (STG_A) stageA(&lA[SD][SKH][0], STGT, SKH);                                 \
        else       stageB(&lB[SD][SKH][0], STGT, SKH);                                 \
        asm volatile("" ::: "memory");                                                 \
        __builtin_amdgcn_s_barrier();                                                  \
        asm volatile("s_waitcnt lgkmcnt(0)" ::: "memory");                             \
        __builtin_amdgcn_s_setprio(1);                                                 \
        _Pragma("unroll")                                                              \
        for (int ii = 0; ii < 4; ++ii)                                                 \
            _Pragma("unroll")                                                          \
            for (int jj = 0; jj < NR; ++jj)                                            \
                acc[MH * 4 + ii][jj] = __builtin_amdgcn_mfma_f32_16x16x32_bf16(        \
                    af[ii], bfrag[jj], acc[MH * 4 + ii][jj], 0, 0, 0);                 \
        __builtin_amdgcn_s_setprio(0);                                                 \
        if (VM_END) VM_WAIT();                                                         \
        asm volatile("" ::: "memory");                                                 \
        __builtin_amdgcn_s_barrier();                                                  \
    }

    const int nt = K >> 6;        // K-tiles of 64 (even: 18 or 72 here)
    const int nIter = nt >> 1;

    // prologue: "iter -1" stages p1..p7 -> tiles 0 (both halves) + tile 1 k0
    // + tile1's B halves; wait leaves the newest 3 slabs in flight.
    stageB(&lB[0][0][0], 0, 0);
    stageA(&lA[0][0][0], 0, 0);
    stageB(&lB[0][1][0], 0, 1);
    stageA(&lA[0][1][0], 0, 1);
    stageB(&lB[1][0][0], 1, 0);
    stageA(&lA[1][0][0], 1, 0);
    stageB(&lB[1][1][0], 1, 1);
    VM_WAIT();
    asm volatile("" ::: "memory");
    __builtin_amdgcn_s_barrier();

    for (int it = 0; it < nIter; ++it) {
        const int T  = it << 1;
        const int t2 = (T + 2 < nt) ? T + 2 : nt - 1;  // clamped dummy stages
        const int t3 = (T + 3 < nt) ? T + 3 : nt - 1;  // keep vmcnt counts exact
        PH(0, 0, 0, true , 1, 1, T + 1, false)   // p1
        PH(0, 0, 1, false, 0, 0, t2,    false)   // p2
        PH(0, 1, 0, true , 0, 0, t2,    false)   // p3
        PH(0, 1, 1, false, 0, 1, t2,    true )   // p4  (vmcnt)
        PH(1, 0, 0, true , 0, 1, t2,    false)   // p5
        PH(1, 0, 1, false, 1, 0, t3,    false)   // p6
        PH(1, 1, 0, true , 1, 0, t3,    false)   // p7
        PH(1, 1, 1, false, 1, 1, t3,    true )   // p8  (vmcnt)
    }
#undef PH
#undef VM_WAIT

    // epilogue: C/D layout col=lane&15 (n), row=quad*4+reg (m); acc row mi -> +mi*16
#pragma unroll
    for (int mi = 0; mi < 8; ++mi) {
#pragma unroll
        for (int r = 0; r < 4; ++r) {
            int m = bm * BM + wm * 128 + mi * 16 + q * 4 + r;
            float sc = rowScale[m];
#pragma unroll
            for (int j = 0; j < NR; ++j) {
                int n = bn * BN + wn * WCN + j * 16 + lr;
                float v = acc[mi][j][r] * sc + bias[n];
                size_t off = (size_t)m * N + n;
                if (GELU) {
                    v = 0.5f * v * (1.f + erff(v * 0.70710678118654752f));
                    ((unsigned short*)C)[off] = f2bf(v);
                } else {
                    ((float*)C)[off] = v;
                }
            }
        }
    }
}

__device__ __forceinline__ float waveMax(float m) {
#pragma unroll
    for (int off = 32; off; off >>= 1) m = fmaxf(m, __shfl_xor(m, off));
    return m;
}

// per-token: gather reorder, absmax, write q (exact in bf16) + scale
__global__ __launch_bounds__(256) void quant_x_kernel(
    const float* __restrict__ x, const int* __restrict__ ridx,
    unsigned short* __restrict__ xq, float* __restrict__ sx, int D)
{
    __shared__ float buf[1152];
    __shared__ float wmax[4];
    const float* xr = x + (size_t)blockIdx.x * D;
    const int tid = threadIdx.x;
    float m = 0.f;
    for (int c = tid; c < D; c += 256) {
        float v = xr[ridx[c]];
        buf[c] = v;
        m = fmaxf(m, fabsf(v));
    }
    m = waveMax(m);
    if ((tid & 63) == 0) wmax[tid >> 6] = m;
    __syncthreads();
    m = fmaxf(fmaxf(wmax[0], wmax[1]), fmaxf(wmax[2], wmax[3]));
    float scale = fmaxf(m * (1.f / 127.f), 1e-8f);
    float inv = 1.f / scale;
    unsigned short* xo = xq + (size_t)blockIdx.x * D;
    for (int c = tid; c < D; c += 256) {
        float qv = fminf(fmaxf(rintf(buf[c] * inv), -128.f), 127.f);
        xo[c] = f2bf(qv);  // exact: integers |q|<=128
    }
    if (tid == 0) sx[blockIdx.x] = scale;
}

// per-token in-place: h(bf16) -> q (exact bf16) + scale
__global__ __launch_bounds__(256) void quant_h_kernel(
    unsigned short* __restrict__ h, float* __restrict__ sh, int H)
{
    __shared__ float buf[4608];
    __shared__ float wmax[4];
    unsigned int* hr = (unsigned int*)(h + (size_t)blockIdx.x * H);
    const int tid = threadIdx.x;
    const int n2 = H >> 1;
    float m = 0.f;
    for (int c = tid; c < n2; c += 256) {
        unsigned int u = hr[c];
        float v0 = bf2f((unsigned short)(u & 0xffffu));
        float v1 = bf2f((unsigned short)(u >> 16));
        buf[2 * c] = v0; buf[2 * c + 1] = v1;
        m = fmaxf(m, fmaxf(fabsf(v0), fabsf(v1)));
    }
    m = waveMax(m);
    if ((tid & 63) == 0) wmax[tid >> 6] = m;
    __syncthreads();
    m = fmaxf(fmaxf(wmax[0], wmax[1]), fmaxf(wmax[2], wmax[3]));
    float scale = fmaxf(m * (1.f / 127.f), 1e-8f);
    float inv = 1.f / scale;
    for (int c = tid; c < n2; c += 256) {
        float q0 = fminf(fmaxf(rintf(buf[2 * c] * inv), -128.f), 127.f);
        float q1 = fminf(fmaxf(rintf(buf[2 * c + 1] * inv), -128.f), 127.f);
        hr[c] = (unsigned int)f2bf(q0) | ((unsigned int)f2bf(q1) << 16);
    }
    if (tid == 0) sh[blockIdx.x] = scale;
}

__global__ __launch_bounds__(256) void cvt_f32_bf16(
    const float* __restrict__ src, unsigned short* __restrict__ dst, long long n)
{
    long long i = ((long long)blockIdx.x * 256 + threadIdx.x) * 4;
    long long stride = (long long)gridDim.x * 1024;
    for (; i < n; i += stride) {
        float4 v = *(const float4*)(src + i);
        ushort4 o;
        o.x = f2bf(v.x); o.y = f2bf(v.y); o.z = f2bf(v.z); o.w = f2bf(v.w);
        *(ushort4*)(dst + i) = o;
    }
}

extern "C" void kernel_launch(void* const* d_in, const int* in_sizes, int n_in,
                              void* d_out, int out_size, void* d_ws, size_t ws_size,
                              hipStream_t stream)
{
    const float* x    = (const float*)d_in[0];
    const int*   ridx = (const int*)d_in[1];
    const float* W1   = (const float*)d_in[2];
    const float* b1   = (const float*)d_in[3];
    const float* W2   = (const float*)d_in[4];
    const float* b2   = (const float*)d_in[5];
    float* out = (float*)d_out;

    const long long D = in_sizes[1];                 // 1152
    const long long H = in_sizes[3];                 // 4608
    const long long M = (long long)in_sizes[0] / D;  // 32768

    auto al = [](size_t v) { return (v + 255) & ~(size_t)255; };
    char* p = (char*)d_ws;
    unsigned short* w1b = (unsigned short*)p; p += al((size_t)(H * D * 2));
    unsigned short* w2b = (unsigned short*)p; p += al((size_t)(D * H * 2));
    size_t used = (size_t)(p - (char*)d_ws);

    // chunk tokens so per-chunk xq/h/scales fit in remaining workspace.
    // BM=256 now -> chunk must be a multiple of 256.
    size_t perTok = (size_t)(D + H) * 2 + 8;
    long long chunk = (long long)((ws_size - used - 4096) / perTok);
    chunk = (chunk / 256) * 256;
    if (chunk > M) chunk = M;
    if (chunk < 256) chunk = 256;  // guard (assumes ws >= ~25 MB)

    unsigned short* xq   = (unsigned short*)p; p += al((size_t)chunk * D * 2);
    unsigned short* hbuf = (unsigned short*)p; p += al((size_t)chunk * H * 2);
    float* sx = (float*)p; p += al((size_t)chunk * 4);
    float* sh = (float*)p;

    cvt_f32_bf16<<<dim3((unsigned)((H * D) / 1024)), 256, 0, stream>>>(W1, w1b, H * D);
    cvt_f32_bf16<<<dim3((unsigned)((D * H) / 1024)), 256, 0, stream>>>(W2, w2b, D * H);

    for (long long r0 = 0; r0 < M; r0 += chunk) {
        long long mc = M - r0; if (mc > chunk) mc = chunk;
        quant_x_kernel<<<dim3((unsigned)mc), 256, 0, stream>>>(
            x + r0 * D, ridx, xq, sx, (int)D);
        unsigned nwg1 = (unsigned)((H / 256) * (mc / 256));
        gemm8p<256, true><<<dim3(nwg1), 512, 0, stream>>>(
            xq, w1b, b1, sx, hbuf, (int)mc, (int)H, (int)D);
        quant_h_kernel<<<dim3((unsigned)mc), 256, 0, stream>>>(hbuf, sh, (int)H);
        unsigned nwg2 = (unsigned)((D / 128) * (mc / 256));
        gemm8p<128, false><<<dim3(nwg2), 512, 0, stream>>>(
            hbuf, w2b, b2, sh, out + r0 * D, (int)mc, (int)D, (int)H);
    }
}